// Round 1
// baseline (583.954 us; speedup 1.0000x reference)
//
#include <hip/hip_runtime.h>

// Problem constants
#define BITN 4
#define RW 8
#define CW 8
#define YR 512
#define IDIM 64
#define ZC 512
#define NROW 4096            // X rows
#define KDIM 4096            // CW*ZC
#define MDIM 4096            // RW*YR

#define GAS __attribute__((address_space(1)))
#define LAS __attribute__((address_space(3)))

typedef __attribute__((ext_vector_type(8))) __bf16 bf16x8;
typedef __attribute__((ext_vector_type(4))) float f32x4;

// ---------- bf16 helpers (bit-exact, no API dependence) ----------
__device__ __forceinline__ unsigned short f2bf_rn(float f) {
    unsigned u = __builtin_bit_cast(unsigned, f);
    unsigned r = (u + 0x7fffu + ((u >> 16) & 1u)) >> 16;   // round-nearest-even
    return (unsigned short)r;
}
__device__ __forceinline__ float bf2f(unsigned short h) {
    return __builtin_bit_cast(float, (unsigned)h << 16);
}
__device__ __forceinline__ void bsplit(float v, unsigned short& h, unsigned short& l) {
    h = f2bf_rn(v);
    float r = v - bf2f(h);
    l = f2bf_rn(r);
}

// ---------- K1: pack Y rows into 64-bit masks (one wave per mask, ballot) ----------
__global__ __launch_bounds__(256) void pack_y_kernel(
    const float* __restrict__ Y, unsigned long long* __restrict__ Ym) {
    const int g = blockIdx.x * 4 + (threadIdx.x >> 6);   // mask index: (b*64+rc)*512 + y
    const int lane = threadIdx.x & 63;
    float v = Y[(size_t)g * 64 + lane];
    unsigned long long m = __ballot(v > 0.5f);
    if (lane == 0) Ym[g] = m;
}

// ---------- K2: pack Z columns into 64-bit masks ----------
__global__ __launch_bounds__(512) void pack_z_kernel(
    const float* __restrict__ Z, unsigned long long* __restrict__ Zm) {
    const int s = blockIdx.x;          // b*64 + rc, rc = rw*8+cw
    const int z = threadIdx.x;         // 0..511
    const size_t base = (size_t)s * 64 * 512;
    unsigned long long m = 0;
#pragma unroll
    for (int i = 0; i < 64; ++i) {
        float v = Z[base + (size_t)i * 512 + z];
        m |= (unsigned long long)(v > 0.5f) << i;
    }
    Zm[(size_t)s * 512 + z] = m;
}

// ---------- K3: W[m,k] = sum_b a*popc(Ym&Zm) + b*popc(Ym) + c*popc(Zm) + d; emit bf16 hi/lo ----------
__global__ __launch_bounds__(512) void build_w_kernel(
    const unsigned long long* __restrict__ Ym, const unsigned long long* __restrict__ Zm,
    const float* __restrict__ Ac, const float* __restrict__ Bc,
    const float* __restrict__ Cc, const float* __restrict__ Dc,
    unsigned short* __restrict__ Whi, unsigned short* __restrict__ Wlo) {
    const int rc = blockIdx.x;             // rw*8+cw
    const int rw = rc >> 3, cw = rc & 7;
    const int yc = blockIdx.y;             // 128-row chunk of y
    const int z = threadIdx.x;             // 0..511

    __shared__ unsigned long long sYm[4][128];
    __shared__ float sYt[128];

    unsigned long long zm[4];
    float Ar[4];
    float czd = Dc[rc];
#pragma unroll
    for (int b = 0; b < 4; ++b) {
        zm[b] = Zm[(size_t)(b * 64 + rc) * 512 + z];
        Ar[b] = Ac[b * 64 + rc];
        czd += Cc[b * 64 + rc] * (float)__popcll(zm[b]);
    }
    {   // stage this chunk's Ym (4 bits x 128 rows)
        int b = z >> 7, y = z & 127;
        sYm[b][y] = Ym[(size_t)(b * 64 + rc) * 512 + yc * 128 + y];
    }
    __syncthreads();
    if (z < 128) {
        float t = 0.f;
#pragma unroll
        for (int b = 0; b < 4; ++b)
            t += Bc[b * 64 + rc] * (float)__popcll(sYm[b][z]);
        sYt[z] = t;
    }
    __syncthreads();

    for (int y = 0; y < 128; ++y) {
        float w = sYt[y] + czd;
#pragma unroll
        for (int b = 0; b < 4; ++b)
            w += Ar[b] * (float)__popcll(sYm[b][y] & zm[b]);
        unsigned short h, l;
        bsplit(w, h, l);
        size_t o = (size_t)(rw * 512 + yc * 128 + y) * KDIM + cw * 512 + z;
        Whi[o] = h;
        Wlo[o] = l;
    }
}

// ---------- K4: split X into bf16 hi/lo ----------
__global__ __launch_bounds__(256) void split_x_kernel(
    const float* __restrict__ X, unsigned short* __restrict__ Xhi, unsigned short* __restrict__ Xlo) {
    const size_t i = (size_t)blockIdx.x * 256 + threadIdx.x;   // 4 floats per thread
    float4 v = reinterpret_cast<const float4*>(X)[i];
    ushort4 h, l;
    bsplit(v.x, h.x, l.x);
    bsplit(v.y, h.y, l.y);
    bsplit(v.z, h.z, l.z);
    bsplit(v.w, h.w, l.w);
    reinterpret_cast<ushort4*>(Xhi)[i] = h;
    reinterpret_cast<ushort4*>(Xlo)[i] = l;
}

// ---------- K5: out = Xhi*Whi^T + Xhi*Wlo^T + Xlo*Whi^T + bias  (m97-style 128x128 tile) ----------
__global__ __launch_bounds__(256) void gemm_split_kernel(
    const unsigned short* __restrict__ Xhi, const unsigned short* __restrict__ Xlo,
    const unsigned short* __restrict__ Whi, const unsigned short* __restrict__ Wlo,
    const float* __restrict__ bias, float* __restrict__ out) {
    __shared__ unsigned short sXh[128 * 32];
    __shared__ unsigned short sXl[128 * 32];
    __shared__ unsigned short sWh[128 * 32];
    __shared__ unsigned short sWl[128 * 32];

    const int tid = threadIdx.x;
    const int lane = tid & 63;
    const int wave = tid >> 6;
    const int wr = wave >> 1, wc = wave & 1;     // 2x2 waves of 64x64
    const int fr = lane & 15, fq = lane >> 4;

    const int row0 = blockIdx.y * 128;           // X-row tile
    const int col0 = blockIdx.x * 128;           // W-row (out col) tile

    // staging geometry: tile = 128 rows x 32 k (bf16) = 8192B; wave-chunk = 1024B = 16 rows
    const int st_row = lane >> 2;        // + c*16
    const int st_k = (lane & 3) * 8;     // ushort offset in row

    f32x4 acc[4][4] = {};

    for (int kt = 0; kt < KDIM; kt += 32) {
        __syncthreads();
#pragma unroll
        for (int r = 0; r < 2; ++r) {
            const int c = r * 4 + wave;
            const int trow = c * 16 + st_row;
            const size_t gA = (size_t)(row0 + trow) * KDIM + kt + st_k;
            const size_t gB = (size_t)(col0 + trow) * KDIM + kt + st_k;
            const int so = c * 512;      // ushort offset (= c*1024 bytes)
            __builtin_amdgcn_global_load_lds((GAS void*)(Xhi + gA), (LAS void*)(sXh + so), 16, 0, 0);
            __builtin_amdgcn_global_load_lds((GAS void*)(Xlo + gA), (LAS void*)(sXl + so), 16, 0, 0);
            __builtin_amdgcn_global_load_lds((GAS void*)(Whi + gB), (LAS void*)(sWh + so), 16, 0, 0);
            __builtin_amdgcn_global_load_lds((GAS void*)(Wlo + gB), (LAS void*)(sWl + so), 16, 0, 0);
        }
        __syncthreads();

        bf16x8 ah[4], al[4], bh[4], bl[4];
#pragma unroll
        for (int m = 0; m < 4; ++m) {
            const int ro = (64 * wr + 16 * m + fr) * 32 + fq * 8;
            ah[m] = *reinterpret_cast<const bf16x8*>(&sXh[ro]);
            al[m] = *reinterpret_cast<const bf16x8*>(&sXl[ro]);
        }
#pragma unroll
        for (int n = 0; n < 4; ++n) {
            const int ro = (64 * wc + 16 * n + fr) * 32 + fq * 8;
            bh[n] = *reinterpret_cast<const bf16x8*>(&sWh[ro]);
            bl[n] = *reinterpret_cast<const bf16x8*>(&sWl[ro]);
        }
#pragma unroll
        for (int m = 0; m < 4; ++m)
#pragma unroll
            for (int n = 0; n < 4; ++n) {
                acc[m][n] = __builtin_amdgcn_mfma_f32_16x16x32_bf16(ah[m], bh[n], acc[m][n], 0, 0, 0);
                acc[m][n] = __builtin_amdgcn_mfma_f32_16x16x32_bf16(ah[m], bl[n], acc[m][n], 0, 0, 0);
                acc[m][n] = __builtin_amdgcn_mfma_f32_16x16x32_bf16(al[m], bh[n], acc[m][n], 0, 0, 0);
            }
    }

    // epilogue: C/D layout col=lane&15, row=4*(lane>>4)+e
    float bvec[4];
#pragma unroll
    for (int n = 0; n < 4; ++n) bvec[n] = bias[col0 + 64 * wc + 16 * n + fr];

#pragma unroll
    for (int m = 0; m < 4; ++m) {
        const int orow = row0 + 64 * wr + 16 * m + 4 * fq;
#pragma unroll
        for (int n = 0; n < 4; ++n) {
            const int ocol = col0 + 64 * wc + 16 * n + fr;
            float* po = out + (size_t)orow * MDIM + ocol;
#pragma unroll
            for (int e = 0; e < 4; ++e)
                po[(size_t)e * MDIM] = acc[m][n][e] + bvec[n];
        }
    }
}

// ---------- launch ----------
extern "C" void kernel_launch(void* const* d_in, const int* in_sizes, int n_in,
                              void* d_out, int out_size, void* d_ws, size_t ws_size,
                              hipStream_t stream) {
    const float* X  = (const float*)d_in[0];
    const float* Y  = (const float*)d_in[1];
    const float* Z  = (const float*)d_in[2];
    const float* Ac = (const float*)d_in[3];
    const float* Bc = (const float*)d_in[4];
    const float* Cc = (const float*)d_in[5];
    const float* Dc = (const float*)d_in[6];
    const float* bias = (const float*)d_in[7];
    float* out = (float*)d_out;

    char* ws = (char*)d_ws;
    // layout: Xhi,Xlo,Whi,Wlo (each 4096*4096*2B = 32MB), Ym (1MB), Zm (1MB)
    unsigned short* Xhi = (unsigned short*)(ws);
    unsigned short* Xlo = (unsigned short*)(ws + (size_t)33554432);
    unsigned short* Whi = (unsigned short*)(ws + (size_t)67108864);
    unsigned short* Wlo = (unsigned short*)(ws + (size_t)100663296);
    unsigned long long* Ym = (unsigned long long*)(ws + (size_t)134217728);
    unsigned long long* Zm = (unsigned long long*)(ws + (size_t)135266304);

    pack_y_kernel<<<32768, 256, 0, stream>>>(Y, Ym);
    pack_z_kernel<<<256, 512, 0, stream>>>(Z, Zm);
    build_w_kernel<<<dim3(64, 4), 512, 0, stream>>>(Ym, Zm, Ac, Bc, Cc, Dc, Whi, Wlo);
    split_x_kernel<<<16384, 256, 0, stream>>>(X, Xhi, Xlo);
    gemm_split_kernel<<<dim3(32, 32), 256, 0, stream>>>(Xhi, Xlo, Whi, Wlo, bias, out);
}

// Round 2
// 397.748 us; speedup vs baseline: 1.4682x; 1.4682x over previous
//
#include <hip/hip_runtime.h>

// Problem constants
#define BITN 4
#define RW 8
#define CW 8
#define YR 512
#define IDIM 64
#define ZC 512
#define NROW 4096            // X rows
#define KDIM 4096            // CW*ZC
#define MDIM 4096            // RW*YR

#define GAS __attribute__((address_space(1)))
#define LAS __attribute__((address_space(3)))

typedef __attribute__((ext_vector_type(8))) _Float16 f16x8;
typedef __attribute__((ext_vector_type(4))) float f32x4;

__device__ __forceinline__ unsigned short f2h(float v) {
    return __builtin_bit_cast(unsigned short, (_Float16)v);
}

// ---------- K1: pack Y rows into 64-bit masks (one wave per mask, ballot) ----------
__global__ __launch_bounds__(256) void pack_y_kernel(
    const float* __restrict__ Y, unsigned long long* __restrict__ Ym) {
    const int g = blockIdx.x * 4 + (threadIdx.x >> 6);   // mask index: (b*64+rc)*512 + y
    const int lane = threadIdx.x & 63;
    float v = Y[(size_t)g * 64 + lane];
    unsigned long long m = __ballot(v > 0.5f);
    if (lane == 0) Ym[g] = m;
}

// ---------- K2: pack Z columns into 64-bit masks ----------
__global__ __launch_bounds__(512) void pack_z_kernel(
    const float* __restrict__ Z, unsigned long long* __restrict__ Zm) {
    const int s = blockIdx.x;          // b*64 + rc, rc = rw*8+cw
    const int z = threadIdx.x;         // 0..511
    const size_t base = (size_t)s * 64 * 512;
    unsigned long long m = 0;
#pragma unroll
    for (int i = 0; i < 64; ++i) {
        float v = Z[base + (size_t)i * 512 + z];
        m |= (unsigned long long)(v > 0.5f) << i;
    }
    Zm[(size_t)s * 512 + z] = m;
}

// ---------- K3: W[m,k] = sum_b a*popc(Ym&Zm) + b*popc(Ym) + c*popc(Zm) + d; emit fp16 ----------
__global__ __launch_bounds__(512) void build_w_kernel(
    const unsigned long long* __restrict__ Ym, const unsigned long long* __restrict__ Zm,
    const float* __restrict__ Ac, const float* __restrict__ Bc,
    const float* __restrict__ Cc, const float* __restrict__ Dc,
    unsigned short* __restrict__ Wh) {
    const int rc = blockIdx.x;             // rw*8+cw
    const int rw = rc >> 3, cw = rc & 7;
    const int yc = blockIdx.y;             // 128-row chunk of y
    const int z = threadIdx.x;             // 0..511

    __shared__ unsigned long long sYm[4][128];
    __shared__ float sYt[128];

    unsigned long long zm[4];
    float Ar[4];
    float czd = Dc[rc];
#pragma unroll
    for (int b = 0; b < 4; ++b) {
        zm[b] = Zm[(size_t)(b * 64 + rc) * 512 + z];
        Ar[b] = Ac[b * 64 + rc];
        czd += Cc[b * 64 + rc] * (float)__popcll(zm[b]);
    }
    {   // stage this chunk's Ym (4 bits x 128 rows)
        int b = z >> 7, y = z & 127;
        sYm[b][y] = Ym[(size_t)(b * 64 + rc) * 512 + yc * 128 + y];
    }
    __syncthreads();
    if (z < 128) {
        float t = 0.f;
#pragma unroll
        for (int b = 0; b < 4; ++b)
            t += Bc[b * 64 + rc] * (float)__popcll(sYm[b][z]);
        sYt[z] = t;
    }
    __syncthreads();

    for (int y = 0; y < 128; ++y) {
        float w = sYt[y] + czd;
#pragma unroll
        for (int b = 0; b < 4; ++b)
            w += Ar[b] * (float)__popcll(sYm[b][y] & zm[b]);
        size_t o = (size_t)(rw * 512 + yc * 128 + y) * KDIM + cw * 512 + z;
        Wh[o] = f2h(w);
    }
}

// ---------- K4: convert X to fp16 ----------
__global__ __launch_bounds__(256) void convert_x_kernel(
    const float* __restrict__ X, unsigned short* __restrict__ Xh) {
    const size_t i = (size_t)blockIdx.x * 256 + threadIdx.x;   // 4 floats per thread
    float4 v = reinterpret_cast<const float4*>(X)[i];
    ushort4 h;
    h.x = f2h(v.x);
    h.y = f2h(v.y);
    h.z = f2h(v.z);
    h.w = f2h(v.w);
    reinterpret_cast<ushort4*>(Xh)[i] = h;
}

// ---------- K5: out = Xh*Wh^T + bias  (m97-style 128x128 tile, fp16 MFMA) ----------
__global__ __launch_bounds__(256) void gemm_f16_kernel(
    const unsigned short* __restrict__ Xh, const unsigned short* __restrict__ Wh,
    const float* __restrict__ bias, float* __restrict__ out) {
    __shared__ unsigned short sX[128 * 32];
    __shared__ unsigned short sW[128 * 32];

    const int tid = threadIdx.x;
    const int lane = tid & 63;
    const int wave = tid >> 6;
    const int wr = wave >> 1, wc = wave & 1;     // 2x2 waves of 64x64
    const int fr = lane & 15, fq = lane >> 4;

    const int row0 = blockIdx.y * 128;           // X-row tile
    const int col0 = blockIdx.x * 128;           // W-row (out col) tile

    // staging geometry: tile = 128 rows x 32 k (fp16) = 8192B; wave-chunk = 1024B = 16 rows
    const int st_row = lane >> 2;        // + c*16
    const int st_k = (lane & 3) * 8;     // ushort offset in row

    f32x4 acc[4][4] = {};

    for (int kt = 0; kt < KDIM; kt += 32) {
        __syncthreads();
#pragma unroll
        for (int r = 0; r < 2; ++r) {
            const int c = r * 4 + wave;
            const int trow = c * 16 + st_row;
            const size_t gA = (size_t)(row0 + trow) * KDIM + kt + st_k;
            const size_t gB = (size_t)(col0 + trow) * KDIM + kt + st_k;
            const int so = c * 512;      // ushort offset (= c*1024 bytes)
            __builtin_amdgcn_global_load_lds((GAS void*)(Xh + gA), (LAS void*)(sX + so), 16, 0, 0);
            __builtin_amdgcn_global_load_lds((GAS void*)(Wh + gB), (LAS void*)(sW + so), 16, 0, 0);
        }
        __syncthreads();

        f16x8 a[4], b[4];
#pragma unroll
        for (int m = 0; m < 4; ++m) {
            const int ro = (64 * wr + 16 * m + fr) * 32 + fq * 8;
            a[m] = *reinterpret_cast<const f16x8*>(&sX[ro]);
        }
#pragma unroll
        for (int n = 0; n < 4; ++n) {
            const int ro = (64 * wc + 16 * n + fr) * 32 + fq * 8;
            b[n] = *reinterpret_cast<const f16x8*>(&sW[ro]);
        }
#pragma unroll
        for (int m = 0; m < 4; ++m)
#pragma unroll
            for (int n = 0; n < 4; ++n)
                acc[m][n] = __builtin_amdgcn_mfma_f32_16x16x32_f16(a[m], b[n], acc[m][n], 0, 0, 0);
    }

    // epilogue: C/D layout col=lane&15, row=4*(lane>>4)+e
    float bvec[4];
#pragma unroll
    for (int n = 0; n < 4; ++n) bvec[n] = bias[col0 + 64 * wc + 16 * n + fr];

#pragma unroll
    for (int m = 0; m < 4; ++m) {
        const int orow = row0 + 64 * wr + 16 * m + 4 * fq;
#pragma unroll
        for (int n = 0; n < 4; ++n) {
            const int ocol = col0 + 64 * wc + 16 * n + fr;
            float* po = out + (size_t)orow * MDIM + ocol;
#pragma unroll
            for (int e = 0; e < 4; ++e)
                po[(size_t)e * MDIM] = acc[m][n][e] + bvec[n];
        }
    }
}

// ---------- launch ----------
extern "C" void kernel_launch(void* const* d_in, const int* in_sizes, int n_in,
                              void* d_out, int out_size, void* d_ws, size_t ws_size,
                              hipStream_t stream) {
    const float* X  = (const float*)d_in[0];
    const float* Y  = (const float*)d_in[1];
    const float* Z  = (const float*)d_in[2];
    const float* Ac = (const float*)d_in[3];
    const float* Bc = (const float*)d_in[4];
    const float* Cc = (const float*)d_in[5];
    const float* Dc = (const float*)d_in[6];
    const float* bias = (const float*)d_in[7];
    float* out = (float*)d_out;

    char* ws = (char*)d_ws;
    // layout: Xh (32MB), Wh (32MB), Ym (1MB), Zm (1MB)
    unsigned short* Xh = (unsigned short*)(ws);
    unsigned short* Wh = (unsigned short*)(ws + (size_t)33554432);
    unsigned long long* Ym = (unsigned long long*)(ws + (size_t)67108864);
    unsigned long long* Zm = (unsigned long long*)(ws + (size_t)68157440);

    pack_y_kernel<<<32768, 256, 0, stream>>>(Y, Ym);
    pack_z_kernel<<<256, 512, 0, stream>>>(Z, Zm);
    build_w_kernel<<<dim3(64, 4), 512, 0, stream>>>(Ym, Zm, Ac, Bc, Cc, Dc, Wh);
    convert_x_kernel<<<16384, 256, 0, stream>>>(X, Xh);
    gemm_f16_kernel<<<dim3(32, 32), 256, 0, stream>>>(Xh, Wh, bias, out);
}

// Round 3
// 333.552 us; speedup vs baseline: 1.7507x; 1.1925x over previous
//
#include <hip/hip_runtime.h>

#define KDIM 4096
#define MDIM 4096
#define GAS __attribute__((address_space(1)))
#define LAS __attribute__((address_space(3)))

typedef __attribute__((ext_vector_type(8))) _Float16 f16x8;
typedef __attribute__((ext_vector_type(4))) float f32x4;

__device__ __forceinline__ unsigned short f2h(float v) {
    return __builtin_bit_cast(unsigned short, (_Float16)v);
}

// ---------- K1: pack Y rows into 64-bit masks ----------
__global__ __launch_bounds__(256) void pack_y_kernel(
    const float* __restrict__ Y, unsigned long long* __restrict__ Ym) {
    const int g = blockIdx.x * 4 + (threadIdx.x >> 6);
    const int lane = threadIdx.x & 63;
    float v = Y[(size_t)g * 64 + lane];
    unsigned long long m = __ballot(v > 0.5f);
    if (lane == 0) Ym[g] = m;
}

// ---------- K2: pack Z columns into 64-bit masks ----------
__global__ __launch_bounds__(512) void pack_z_kernel(
    const float* __restrict__ Z, unsigned long long* __restrict__ Zm) {
    const int s = blockIdx.x;
    const int z = threadIdx.x;
    const size_t base = (size_t)s * 64 * 512;
    unsigned long long m = 0;
#pragma unroll
    for (int i = 0; i < 64; ++i) {
        float v = Z[base + (size_t)i * 512 + z];
        m |= (unsigned long long)(v > 0.5f) << i;
    }
    Zm[(size_t)s * 512 + z] = m;
}

// ---------- K3: build W in fp16 (2048 blocks, ushort4 stores) ----------
__global__ __launch_bounds__(512) void build_w_kernel(
    const unsigned long long* __restrict__ Ym, const unsigned long long* __restrict__ Zm,
    const float* __restrict__ Ac, const float* __restrict__ Bc,
    const float* __restrict__ Cc, const float* __restrict__ Dc,
    unsigned short* __restrict__ Wh) {
    const int rc = blockIdx.x;             // 0..63
    const int rw = rc >> 3, cw = rc & 7;
    const int yc = blockIdx.y;             // 0..31, 16 y-rows each
    const int tid = threadIdx.x;
    const int zq = tid & 127;              // z = zq*4 .. +3
    const int ys = tid >> 7;               // 0..3

    __shared__ unsigned long long sYm[4][16];

    float Ar[4], Br[4];
    float dval = Dc[rc];
    float czd4[4] = {dval, dval, dval, dval};
    unsigned long long zm[4][4];
#pragma unroll
    for (int b = 0; b < 4; ++b) {
        Ar[b] = Ac[b * 64 + rc];
        Br[b] = Bc[b * 64 + rc];
        float cb = Cc[b * 64 + rc];
        const unsigned long long* zp = Zm + (size_t)(b * 64 + rc) * 512 + zq * 4;
#pragma unroll
        for (int j = 0; j < 4; ++j) {
            zm[b][j] = zp[j];
            czd4[j] += cb * (float)__popcll(zm[b][j]);
        }
    }
    if (tid < 64)
        sYm[tid >> 4][tid & 15] = Ym[(size_t)((tid >> 4) * 64 + rc) * 512 + yc * 16 + (tid & 15)];
    __syncthreads();

#pragma unroll
    for (int yy = 0; yy < 4; ++yy) {
        const int yl = ys * 4 + yy;
        unsigned long long ym[4];
        float bt = 0.f;
#pragma unroll
        for (int b = 0; b < 4; ++b) {
            ym[b] = sYm[b][yl];
            bt += Br[b] * (float)__popcll(ym[b]);
        }
        ushort4 o4;
        float w0 = bt + czd4[0], w1 = bt + czd4[1], w2 = bt + czd4[2], w3 = bt + czd4[3];
#pragma unroll
        for (int b = 0; b < 4; ++b) {
            w0 += Ar[b] * (float)__popcll(ym[b] & zm[b][0]);
            w1 += Ar[b] * (float)__popcll(ym[b] & zm[b][1]);
            w2 += Ar[b] * (float)__popcll(ym[b] & zm[b][2]);
            w3 += Ar[b] * (float)__popcll(ym[b] & zm[b][3]);
        }
        o4.x = f2h(w0); o4.y = f2h(w1); o4.z = f2h(w2); o4.w = f2h(w3);
        size_t o = (size_t)(rw * 512 + yc * 16 + yl) * KDIM + cw * 512 + zq * 4;
        *reinterpret_cast<ushort4*>(&Wh[o]) = o4;
    }
}

// ---------- K4: convert X to fp16 ----------
__global__ __launch_bounds__(256) void convert_x_kernel(
    const float* __restrict__ X, unsigned short* __restrict__ Xh) {
    const size_t i = (size_t)blockIdx.x * 256 + threadIdx.x;
    float4 v = reinterpret_cast<const float4*>(X)[i];
    ushort4 h;
    h.x = f2h(v.x); h.y = f2h(v.y); h.z = f2h(v.z); h.w = f2h(v.w);
    reinterpret_cast<ushort4*>(Xh)[i] = h;
}

// ---------- K5: 256x256 tile, BK=32, triple-buffered counted-vmcnt GEMM ----------
// LDS swizzle: linear tile byte e (= prow*128 + (row&1)*64 + k*2, prow=row>>1)
// stored at byte e ^ ((prow&7)<<4). Involution; staging pre-applies inverse to
// the GLOBAL source address (rule #21), global_load_lds dest stays linear.
__global__ __launch_bounds__(512) void gemm_f16_kernel(
    const unsigned short* __restrict__ Xh, const unsigned short* __restrict__ Wh,
    const float* __restrict__ bias, float* __restrict__ out) {
    __shared__ unsigned short smem[49152];   // 96 KB: 3 bufs x (A 8192 + B 8192 ushorts)

    const int tid = threadIdx.x;
    const int lane = tid & 63;
    const int wave = tid >> 6;
    const int wr = wave >> 2, wc = wave & 3;   // 2 x 4 waves; per-wave out = 128x64
    const int fr = lane & 15, fq = lane >> 4;

    // XCD-aware bijective swizzle (256 blocks, 256%8==0)
    const int bid = blockIdx.x;
    const int swz = (bid & 7) * 32 + (bid >> 3);
    const int bx = swz & 15, by = swz >> 4;
    const int row0 = by * 256, col0 = bx * 256;

    // staging: per-thread global offset for dest d = uh*8192 + tid*16 (region bytes)
    int goff[2];
#pragma unroll
    for (int uh = 0; uh < 2; ++uh) {
        int d = uh * 8192 + tid * 16;
        int e = d ^ (((d >> 7) & 7) << 4);
        int rowl = ((e >> 7) << 1) | ((e >> 6) & 1);
        int kel = (e >> 1) & 31;
        goff[uh] = rowl * KDIM + kel;
    }

    // ds_read indices (ushort units, region-local), swizzled
    const int sw = (fr >> 1) << 3;
    int idxA[8], idxB[4];
#pragma unroll
    for (int m = 0; m < 8; ++m)
        idxA[m] = ((wr * 64 + m * 8 + (fr >> 1)) * 64 + (fr & 1) * 32 + fq * 8) ^ sw;
#pragma unroll
    for (int n = 0; n < 4; ++n)
        idxB[n] = ((wc * 32 + n * 8 + (fr >> 1)) * 64 + (fr & 1) * 32 + fq * 8) ^ sw;

    const unsigned short* Abase = Xh + (size_t)row0 * KDIM;
    const unsigned short* Bbase = Wh + (size_t)col0 * KDIM;
    const int ldsw = wave * 512;

    f32x4 acc[8][4] = {};

    // prologue: stage tiles 0 -> buf0, 1 -> buf1 (4 loads each)
#pragma unroll
    for (int t = 0; t < 2; ++t) {
        const int ub = t * 16384;
#pragma unroll
        for (int uh = 0; uh < 2; ++uh) {
            __builtin_amdgcn_global_load_lds((GAS void*)(Abase + t * 32 + goff[uh]),
                (LAS void*)(smem + ub + uh * 4096 + ldsw), 16, 0, 0);
            __builtin_amdgcn_global_load_lds((GAS void*)(Bbase + t * 32 + goff[uh]),
                (LAS void*)(smem + ub + 8192 + uh * 4096 + ldsw), 16, 0, 0);
        }
    }
    asm volatile("s_waitcnt vmcnt(4)" ::: "memory");   // tile0 resident, tile1 in flight
    __builtin_amdgcn_s_barrier();

    int cb = 0;   // current buffer ushort base (0 / 16384 / 32768)
    for (int t = 0; t < 128; ++t) {
        const int nb = (cb >= 16384) ? cb - 16384 : cb + 32768;   // buffer (t+2)%3
        const int tk = (t < 126) ? (t + 2) * 32 : 0;              // clamp keeps vmcnt uniform

        // ---- phase A: frags m0..3 + all B, stage A-halves of t+2 ----
        f16x8 a0[4], bfr[4];
#pragma unroll
        for (int m = 0; m < 4; ++m) a0[m] = *reinterpret_cast<const f16x8*>(&smem[cb + idxA[m]]);
#pragma unroll
        for (int n = 0; n < 4; ++n) bfr[n] = *reinterpret_cast<const f16x8*>(&smem[cb + 8192 + idxB[n]]);
#pragma unroll
        for (int uh = 0; uh < 2; ++uh)
            __builtin_amdgcn_global_load_lds((GAS void*)(Abase + tk + goff[uh]),
                (LAS void*)(smem + nb + uh * 4096 + ldsw), 16, 0, 0);
        __builtin_amdgcn_s_barrier();
        __builtin_amdgcn_s_setprio(1);
#pragma unroll
        for (int m = 0; m < 4; ++m)
#pragma unroll
            for (int n = 0; n < 4; ++n)
                acc[m][n] = __builtin_amdgcn_mfma_f32_16x16x32_f16(a0[m], bfr[n], acc[m][n], 0, 0, 0);
        __builtin_amdgcn_s_setprio(0);
        __builtin_amdgcn_s_barrier();

        // ---- phase B: frags m4..7, stage B-halves of t+2 ----
        f16x8 a1[4];
#pragma unroll
        for (int m = 0; m < 4; ++m) a1[m] = *reinterpret_cast<const f16x8*>(&smem[cb + idxA[4 + m]]);
#pragma unroll
        for (int uh = 0; uh < 2; ++uh)
            __builtin_amdgcn_global_load_lds((GAS void*)(Bbase + tk + goff[uh]),
                (LAS void*)(smem + nb + 8192 + uh * 4096 + ldsw), 16, 0, 0);
        __builtin_amdgcn_s_barrier();
        __builtin_amdgcn_s_setprio(1);
#pragma unroll
        for (int m = 0; m < 4; ++m)
#pragma unroll
            for (int n = 0; n < 4; ++n)
                acc[4 + m][n] = __builtin_amdgcn_mfma_f32_16x16x32_f16(a1[m], bfr[n], acc[4 + m][n], 0, 0, 0);
        __builtin_amdgcn_s_setprio(0);
        asm volatile("s_waitcnt vmcnt(4)" ::: "memory");   // t+1 resident, t+2 (4 loads) in flight
        __builtin_amdgcn_s_barrier();

        cb = (cb == 32768) ? 0 : cb + 16384;
    }
    asm volatile("s_waitcnt vmcnt(0)" ::: "memory");   // drain before LDS dealloc

    // ---- epilogue ----
    float bv[4];
#pragma unroll
    for (int n = 0; n < 4; ++n) bv[n] = bias[col0 + wc * 64 + n * 16 + fr];

#pragma unroll
    for (int m = 0; m < 8; ++m) {
        const int orow = row0 + wr * 128 + m * 16 + fq * 4;
#pragma unroll
        for (int n = 0; n < 4; ++n) {
            const int ocol = col0 + wc * 64 + n * 16 + fr;
            float* po = out + (size_t)orow * MDIM + ocol;
#pragma unroll
            for (int e = 0; e < 4; ++e)
                po[(size_t)e * MDIM] = acc[m][n][e] + bv[n];
        }
    }
}

// ---------- launch ----------
extern "C" void kernel_launch(void* const* d_in, const int* in_sizes, int n_in,
                              void* d_out, int out_size, void* d_ws, size_t ws_size,
                              hipStream_t stream) {
    const float* X  = (const float*)d_in[0];
    const float* Y  = (const float*)d_in[1];
    const float* Z  = (const float*)d_in[2];
    const float* Ac = (const float*)d_in[3];
    const float* Bc = (const float*)d_in[4];
    const float* Cc = (const float*)d_in[5];
    const float* Dc = (const float*)d_in[6];
    const float* bias = (const float*)d_in[7];
    float* out = (float*)d_out;

    char* ws = (char*)d_ws;
    unsigned short* Xh = (unsigned short*)(ws);
    unsigned short* Wh = (unsigned short*)(ws + (size_t)33554432);
    unsigned long long* Ym = (unsigned long long*)(ws + (size_t)67108864);
    unsigned long long* Zm = (unsigned long long*)(ws + (size_t)68157440);

    pack_y_kernel<<<32768, 256, 0, stream>>>(Y, Ym);
    pack_z_kernel<<<256, 512, 0, stream>>>(Z, Zm);
    build_w_kernel<<<dim3(64, 32), 512, 0, stream>>>(Ym, Zm, Ac, Bc, Cc, Dc, Wh);
    convert_x_kernel<<<16384, 256, 0, stream>>>(X, Xh);
    gemm_f16_kernel<<<dim3(256), 512, 0, stream>>>(Xh, Wh, bias, out);
}